// Round 10
// baseline (283.420 us; speedup 1.0000x reference)
//
#include <hip/hip_runtime.h>

#define U_   2048
#define T_   200
#define S_   10
#define K_   20
#define H_   16
#define DU_  32
#define DE_  32
#define DIN_ 264   // 32 + 11 + 220 + 1

// ---------------------------------------------------------------------------
// Kernel 1: pre[pos,h] = b_rnn[h] + x[pos,:] . Wx[:,h]
// R9 structure (thread-per-position, SGPR weights, no LDS/barriers/shuffles,
// high occupancy) + LINE-BURST loads: each 128B line's 8 float4s issued
// back-to-back so the TCP MSHRs merge them into ONE HBM fetch (no reliance
// on L1/L2 residency across issue windows -> kills the R9 1.8x over-fetch).
// ---------------------------------------------------------------------------
__global__ __launch_bounds__(256, 6) void k_pre(
    const float* __restrict__ q, const float* __restrict__ f,
    const int* __restrict__ docid, const float* __restrict__ ct,
    const float* __restrict__ emb, const float* __restrict__ Wx,
    const float* __restrict__ brnn, float* __restrict__ pre)
{
    const int idx = blockIdx.x * 256 + threadIdx.x;   // 1600 blocks exact

    float acc[H_];
#pragma unroll
    for (int h = 0; h < H_; ++h) acc[h] = brnn[h];    // uniform -> s_load

    const float4* f4 = (const float4*)(f + (size_t)idx * (S_ * K_));  // 800B row

    // ---- f granules 0..47 in six 128B line-bursts (Wx rows 43..234) ----
#pragma unroll 1
    for (int g = 0; g < 6; ++g) {
        float4 v[8];
#pragma unroll
        for (int j = 0; j < 8; ++j) v[j] = f4[g * 8 + j];   // 8 loads, one line
#pragma unroll
        for (int j = 0; j < 8; ++j) {
            const float* w = Wx + (43 + (g * 8 + j) * 4) * H_;   // uniform -> s_load
#pragma unroll
            for (int h = 0; h < H_; ++h)
                acc[h] += v[j].x * w[h] + v[j].y * w[h + 16]
                        + v[j].z * w[h + 32] + v[j].w * w[h + 48];
        }
    }

    // ---- f tail granules 48,49 (Wx rows 235..242) ----
    {
        float4 v0 = f4[48], v1 = f4[49];
        const float* w0 = Wx + (43 + 192) * H_;
        const float* w1 = Wx + (43 + 196) * H_;
#pragma unroll
        for (int h = 0; h < H_; ++h)
            acc[h] += v0.x * w0[h] + v0.y * w0[h + 16] + v0.z * w0[h + 32] + v0.w * w0[h + 48]
                    + v1.x * w1[h] + v1.y * w1[h + 16] + v1.z * w1[h + 32] + v1.w * w1[h + 48];
    }

    // ---- embedding part: Wx rows 0..31 (gather, L2/L3-served) ----
    {
        const float4* e4 = (const float4*)(emb + (size_t)docid[idx] * DE_);
        float4 v[8];
#pragma unroll
        for (int r = 0; r < 8; ++r) v[r] = e4[r];           // one-line burst too
#pragma unroll
        for (int r = 0; r < 8; ++r) {
            const float* w = Wx + (r * 4) * H_;             // uniform
#pragma unroll
            for (int h = 0; h < H_; ++h)
                acc[h] += v[r].x * w[h] + v[r].y * w[h + 16]
                        + v[r].z * w[h + 32] + v[r].w * w[h + 48];
        }
    }

    // ---- quality part: Wx rows 32..41 ----
    {
        const float2* q2 = (const float2*)(q + (size_t)idx * S_);
        float2 v[5];
#pragma unroll
        for (int r = 0; r < 5; ++r) v[r] = q2[r];
#pragma unroll
        for (int r = 0; r < 5; ++r) {
            const float* w = Wx + (DE_ + r * 2) * H_;       // uniform
#pragma unroll
            for (int h = 0; h < H_; ++h)
                acc[h] += v[r].x * w[h] + v[r].y * w[h + 16];
        }
    }

    // ---- ctime: Wx row 263 ----
    {
        float c = ct[idx];
        const float* w = Wx + (DIN_ - 1) * H_;              // uniform
#pragma unroll
        for (int h = 0; h < H_; ++h) acc[h] += c * w[h];
    }

    float4* o = (float4*)(pre + (size_t)idx * H_);
    o[0] = make_float4(acc[0], acc[1], acc[2], acc[3]);
    o[1] = make_float4(acc[4], acc[5], acc[6], acc[7]);
    o[2] = make_float4(acc[8], acc[9], acc[10], acc[11]);
    o[3] = make_float4(acc[12], acc[13], acc[14], acc[15]);
}

// ---------------------------------------------------------------------------
// Kernel 2: sequential RNN scan per user (16 lanes = 16 h-components),
// fused LeakyReLU + Dense(32).  (unchanged)
// ---------------------------------------------------------------------------
__device__ __forceinline__ float tanh_fast(float x) {
    float e = __expf(2.f * x);
    return 1.f - 2.f / (e + 1.f);
}

__global__ __launch_bounds__(64) void k_rnn(
    const float* __restrict__ pre, const int* __restrict__ docid,
    const float* __restrict__ Wh, const float* __restrict__ Wd,
    const float* __restrict__ bd, float* __restrict__ out)
{
    const int tid = threadIdx.x;
    const int l = tid & 15;
    const int u = (blockIdx.x * 64 + tid) >> 4;

    const float* prow = pre + (size_t)u * T_ * H_;
    const int* drow = docid + (size_t)u * T_;

    float wh[16];
#pragma unroll
    for (int k = 0; k < 16; ++k) wh[k] = Wh[((l ^ k) << 4) | l];

    float h = 0.f;

    float pb0 = prow[0 * H_ + l], pb1 = prow[1 * H_ + l],
          pb2 = prow[2 * H_ + l], pb3 = prow[3 * H_ + l];
    int   m0 = drow[0], m1 = drow[1], m2 = drow[2], m3 = drow[3];

    for (int tb = 0; tb < T_; tb += 4) {
#pragma unroll
        for (int s = 0; s < 4; ++s) {
            float p; int m;
            if      (s == 0) { p = pb0; m = m0; }
            else if (s == 1) { p = pb1; m = m1; }
            else if (s == 2) { p = pb2; m = m2; }
            else             { p = pb3; m = m3; }

            int tn = tb + 4 + s; if (tn > T_ - 1) tn = T_ - 1;
            float pn = prow[tn * H_ + l];
            int   mn = drow[tn];
            if      (s == 0) { pb0 = pn; m0 = mn; }
            else if (s == 1) { pb1 = pn; m1 = mn; }
            else if (s == 2) { pb2 = pn; m2 = mn; }
            else             { pb3 = pn; m3 = mn; }

            float a0 = p, a1 = 0.f, a2 = 0.f, a3 = 0.f;
#pragma unroll
            for (int k = 0; k < 16; k += 4) {
                a0 += __shfl_xor(h, k + 0, 16) * wh[k + 0];
                a1 += __shfl_xor(h, k + 1, 16) * wh[k + 1];
                a2 += __shfl_xor(h, k + 2, 16) * wh[k + 2];
                a3 += __shfl_xor(h, k + 3, 16) * wh[k + 3];
            }
            float accv = (a0 + a1) + (a2 + a3);
            float th = tanh_fast(accv);
            h = (m != 0) ? th : h;
        }
    }

    float a = (h >= 0.f) ? h : 0.3f * h;

    float wd0[16], wd1[16];
#pragma unroll
    for (int k = 0; k < 16; ++k) {
        int j = l ^ k;
        wd0[k] = Wd[j * DU_ + l];
        wd1[k] = Wd[j * DU_ + l + 16];
    }
    float o0 = bd[l], o1 = bd[l + 16];
#pragma unroll
    for (int k = 0; k < 16; ++k) {
        float av = __shfl_xor(a, k, 16);
        o0 += av * wd0[k];
        o1 += av * wd1[k];
    }
    out[(size_t)u * DU_ + l] = o0;
    out[(size_t)u * DU_ + l + 16] = o1;
}

// ---------------------------------------------------------------------------
extern "C" void kernel_launch(void* const* d_in, const int* in_sizes, int n_in,
                              void* d_out, int out_size, void* d_ws, size_t ws_size,
                              hipStream_t stream) {
    const float* q     = (const float*)d_in[0];
    const float* f     = (const float*)d_in[1];
    const int*   docid = (const int*)  d_in[2];
    const float* ct    = (const float*)d_in[3];
    const float* emb   = (const float*)d_in[4];
    const float* Wx    = (const float*)d_in[5];
    const float* Wh    = (const float*)d_in[6];
    const float* brnn  = (const float*)d_in[7];
    const float* Wd    = (const float*)d_in[8];
    const float* bd    = (const float*)d_in[9];
    float* out = (float*)d_out;

    float* pre = (float*)d_ws;                   // U*T*H floats = 26.2 MB

    k_pre<<<(U_ * T_) / 256, 256, 0, stream>>>(q, f, docid, ct, emb, Wx, brnn, pre);
    k_rnn<<<(U_ * H_) / 64, 64, 0, stream>>>(pre, docid, Wh, Wd, bd, out);
}

// Round 11
// 174.494 us; speedup vs baseline: 1.6242x; 1.6242x over previous
//
#include <hip/hip_runtime.h>

#define U_   2048
#define T_   200
#define S_   10
#define K_   20
#define H_   16
#define DU_  32
#define DE_  32
#define DIN_ 264   // 32 + 11 + 220 + 1

#define KPAD 224   // f K-dim 200 padded to 7 slabs of 32

typedef __attribute__((ext_vector_type(8))) short bf16x8;
typedef __attribute__((ext_vector_type(4))) float f32x4;

__device__ __forceinline__ unsigned short bf16_rne(float x) {
    unsigned u = __float_as_uint(x);
    return (unsigned short)((u + 0x7FFFu + ((u >> 16) & 1u)) >> 16);
}

// ---------------------------------------------------------------------------
// Kernel 0: W prep — WT_hi/lo[n][k] = bf16 split of Wx[43+k][n], zero k>=200.
// ---------------------------------------------------------------------------
__global__ __launch_bounds__(256) void k_wprep(
    const float* __restrict__ Wx,
    unsigned short* __restrict__ WThi, unsigned short* __restrict__ WTlo)
{
    const int idx = blockIdx.x * 256 + threadIdx.x;      // 16*224 = 3584
    if (idx >= 16 * KPAD) return;
    const int n = idx / KPAD, k = idx - n * KPAD;
    const float wv = (k < 200) ? Wx[(43 + k) * H_ + n] : 0.f;
    const unsigned short h = bf16_rne(wv);
    const float hf = __uint_as_float((unsigned)h << 16);
    WThi[idx] = h;
    WTlo[idx] = bf16_rne(wv - hf);
}

// ---------------------------------------------------------------------------
// Kernel 1a: pre[pos,h] = f[pos,:] . Wx[43:243,h]  via MFMA (3-pass hi/lo).
// 4 independent waves/block (NO barriers). Wave = 64 positions; 7 K-slabs
// of 32 cols. Per slab: 8x dwordx4 (8 lanes/row -> 8 lanes share each line),
// f32->bf16 hi/lo cvt in regs, ds_write to private pane, ds_read frags,
// 12 MFMAs. Next slab's loads issued first -> counted vmcnt keeps ~8KB/wave
// in flight continuously. MfmaUtil goes nonzero for the first time.
// ---------------------------------------------------------------------------
__global__ __launch_bounds__(256, 4) void k_pre_f(
    const float* __restrict__ f,
    const unsigned short* __restrict__ WThi,
    const unsigned short* __restrict__ WTlo,
    float* __restrict__ pre)
{
    __shared__ unsigned short lds_hi[4][64][32];   // 16 KB
    __shared__ unsigned short lds_lo[4][64][32];   // 16 KB
    const int t = threadIdx.x;
    const int l = t & 63;
    const int w = t >> 6;
    const int rbase = blockIdx.x * 256 + w * 64;   // wave's first position
    const char* fB = (const char*)f;

    f32x4 acc[4];
#pragma unroll
    for (int fi = 0; fi < 4; ++fi) acc[fi] = (f32x4){0.f, 0.f, 0.f, 0.f};

    auto LOADF = [&](float4* dst, int s) {
        if (s < 6) {
#pragma unroll
            for (int i = 0; i < 8; ++i) {
                const int row = rbase + i * 8 + (l >> 3);
                dst[i] = *(const float4*)(fB + (size_t)row * 800 + s * 128 + (l & 7) * 16);
            }
        } else {   // slab 6: cols 192..199 -> 32B per row
#pragma unroll
            for (int i = 0; i < 2; ++i) {
                const int row = rbase + i * 32 + (l >> 1);
                dst[i] = *(const float4*)(fB + (size_t)row * 800 + 768 + (l & 1) * 16);
            }
        }
    };

    auto WR4 = [&](int pos, int kq, float4 v) {
        const unsigned short h0 = bf16_rne(v.x), h1 = bf16_rne(v.y),
                             h2 = bf16_rne(v.z), h3 = bf16_rne(v.w);
        const float r0 = v.x - __uint_as_float((unsigned)h0 << 16);
        const float r1 = v.y - __uint_as_float((unsigned)h1 << 16);
        const float r2 = v.z - __uint_as_float((unsigned)h2 << 16);
        const float r3 = v.w - __uint_as_float((unsigned)h3 << 16);
        uint2 hv, lv;
        hv.x = (unsigned)h0 | ((unsigned)h1 << 16);
        hv.y = (unsigned)h2 | ((unsigned)h3 << 16);
        lv.x = (unsigned)bf16_rne(r0) | ((unsigned)bf16_rne(r1) << 16);
        lv.y = (unsigned)bf16_rne(r2) | ((unsigned)bf16_rne(r3) << 16);
        *(uint2*)&lds_hi[w][pos][kq] = hv;
        *(uint2*)&lds_lo[w][pos][kq] = lv;
    };

    auto CVTW = [&](const float4* src, int s) {
        if (s < 6) {
#pragma unroll
            for (int i = 0; i < 8; ++i)
                WR4(i * 8 + (l >> 3), (l & 7) * 4, src[i]);
        } else {
#pragma unroll
            for (int i = 0; i < 2; ++i)
                WR4(i * 32 + (l >> 1), (l & 1) * 4, src[i]);
            // k 8..31 of slab 6 hold stale finite bf16 (slab 5) x zero weights = 0
        }
    };

    float4 bufA[8], bufB[8];
    LOADF(bufA, 0);

#pragma unroll
    for (int s = 0; s < 7; ++s) {
        const float4* cur = (s & 1) ? bufB : bufA;
        float4* nxt = (s & 1) ? bufA : bufB;
        if (s < 6) LOADF(nxt, s + 1);          // issued before cur is consumed

        CVTW(cur, s);                           // compiler: counted vmcnt for cur

        // B fragments (L1/L2-hot after first blocks)
        const bf16x8 bh = *(const bf16x8*)(WThi + (l & 15) * KPAD + s * 32 + (l >> 4) * 8);
        const bf16x8 bl = *(const bf16x8*)(WTlo + (l & 15) * KPAD + s * 32 + (l >> 4) * 8);

#pragma unroll
        for (int fi = 0; fi < 4; ++fi) {
            const int pl_ = fi * 16 + (l & 15);
            const bf16x8 ah = *(const bf16x8*)&lds_hi[w][pl_][(l >> 4) * 8];
            const bf16x8 al = *(const bf16x8*)&lds_lo[w][pl_][(l >> 4) * 8];
            acc[fi] = __builtin_amdgcn_mfma_f32_16x16x32_bf16(ah, bh, acc[fi], 0, 0, 0);
            acc[fi] = __builtin_amdgcn_mfma_f32_16x16x32_bf16(al, bh, acc[fi], 0, 0, 0);
            acc[fi] = __builtin_amdgcn_mfma_f32_16x16x32_bf16(ah, bl, acc[fi], 0, 0, 0);
        }
    }

    // D layout (m89-verified): col = lane&15, row = (lane>>4)*4 + reg
#pragma unroll
    for (int fi = 0; fi < 4; ++fi) {
#pragma unroll
        for (int r = 0; r < 4; ++r) {
            const int pos = rbase + fi * 16 + (l >> 4) * 4 + r;
            pre[(size_t)pos * H_ + (l & 15)] = acc[fi][r];
        }
    }
}

// ---------------------------------------------------------------------------
// Kernel 1b: pre[pos,h] += b_rnn[h] + emb/q/ct parts.  (R7-verified)
// ---------------------------------------------------------------------------
__global__ __launch_bounds__(256) void k_emb(
    const float* __restrict__ q, const int* __restrict__ docid,
    const float* __restrict__ ct, const float* __restrict__ emb,
    const float* __restrict__ Wx, const float* __restrict__ brnn,
    float* __restrict__ pre)
{
    const int idx = blockIdx.x * 256 + threadIdx.x;

    float acc[H_];
#pragma unroll
    for (int h = 0; h < H_; ++h) acc[h] = brnn[h];

    {
        const float4* e4 = (const float4*)(emb + (size_t)docid[idx] * DE_);
#pragma unroll
        for (int r = 0; r < DE_ / 4; ++r) {
            const float4 v = e4[r];
            const float* wt = Wx + (r * 4) * H_;
#pragma unroll
            for (int h = 0; h < H_; ++h)
                acc[h] += v.x * wt[h] + v.y * wt[h + 16] + v.z * wt[h + 32] + v.w * wt[h + 48];
        }
    }
    {
        const float2* q2 = (const float2*)(q + (size_t)idx * S_);
#pragma unroll
        for (int r = 0; r < S_ / 2; ++r) {
            const float2 v = q2[r];
            const float* wt = Wx + (DE_ + 2 * r) * H_;
#pragma unroll
            for (int h = 0; h < H_; ++h)
                acc[h] += v.x * wt[h] + v.y * wt[h + 16];
        }
    }
    {
        const float c = ct[idx];
        const float* wt = Wx + (DIN_ - 1) * H_;
#pragma unroll
        for (int h = 0; h < H_; ++h) acc[h] += c * wt[h];
    }

    float4* o = (float4*)(pre + (size_t)idx * H_);
    float4 p0 = o[0], p1 = o[1], p2 = o[2], p3 = o[3];
    o[0] = make_float4(p0.x + acc[0],  p0.y + acc[1],  p0.z + acc[2],  p0.w + acc[3]);
    o[1] = make_float4(p1.x + acc[4],  p1.y + acc[5],  p1.z + acc[6],  p1.w + acc[7]);
    o[2] = make_float4(p2.x + acc[8],  p2.y + acc[9],  p2.z + acc[10], p2.w + acc[11]);
    o[3] = make_float4(p3.x + acc[12], p3.y + acc[13], p3.z + acc[14], p3.w + acc[15]);
}

// ---------------------------------------------------------------------------
// Kernel 2: sequential RNN scan + LeakyReLU + Dense.  (unchanged)
// ---------------------------------------------------------------------------
__device__ __forceinline__ float tanh_fast(float x) {
    float e = __expf(2.f * x);
    return 1.f - 2.f / (e + 1.f);
}

__global__ __launch_bounds__(64) void k_rnn(
    const float* __restrict__ pre, const int* __restrict__ docid,
    const float* __restrict__ Wh, const float* __restrict__ Wd,
    const float* __restrict__ bd, float* __restrict__ out)
{
    const int tid = threadIdx.x;
    const int l = tid & 15;
    const int u = (blockIdx.x * 64 + tid) >> 4;

    const float* prow = pre + (size_t)u * T_ * H_;
    const int* drow = docid + (size_t)u * T_;

    float wh[16];
#pragma unroll
    for (int k = 0; k < 16; ++k) wh[k] = Wh[((l ^ k) << 4) | l];

    float h = 0.f;

    float pb0 = prow[0 * H_ + l], pb1 = prow[1 * H_ + l],
          pb2 = prow[2 * H_ + l], pb3 = prow[3 * H_ + l];
    int   m0 = drow[0], m1 = drow[1], m2 = drow[2], m3 = drow[3];

    for (int tb = 0; tb < T_; tb += 4) {
#pragma unroll
        for (int s = 0; s < 4; ++s) {
            float p; int m;
            if      (s == 0) { p = pb0; m = m0; }
            else if (s == 1) { p = pb1; m = m1; }
            else if (s == 2) { p = pb2; m = m2; }
            else             { p = pb3; m = m3; }

            int tn = tb + 4 + s; if (tn > T_ - 1) tn = T_ - 1;
            float pn = prow[tn * H_ + l];
            int   mn = drow[tn];
            if      (s == 0) { pb0 = pn; m0 = mn; }
            else if (s == 1) { pb1 = pn; m1 = mn; }
            else if (s == 2) { pb2 = pn; m2 = mn; }
            else             { pb3 = pn; m3 = mn; }

            float a0 = p, a1 = 0.f, a2 = 0.f, a3 = 0.f;
#pragma unroll
            for (int k = 0; k < 16; k += 4) {
                a0 += __shfl_xor(h, k + 0, 16) * wh[k + 0];
                a1 += __shfl_xor(h, k + 1, 16) * wh[k + 1];
                a2 += __shfl_xor(h, k + 2, 16) * wh[k + 2];
                a3 += __shfl_xor(h, k + 3, 16) * wh[k + 3];
            }
            float accv = (a0 + a1) + (a2 + a3);
            float th = tanh_fast(accv);
            h = (m != 0) ? th : h;
        }
    }

    float a = (h >= 0.f) ? h : 0.3f * h;

    float wd0[16], wd1[16];
#pragma unroll
    for (int k = 0; k < 16; ++k) {
        int j = l ^ k;
        wd0[k] = Wd[j * DU_ + l];
        wd1[k] = Wd[j * DU_ + l + 16];
    }
    float o0 = bd[l], o1 = bd[l + 16];
#pragma unroll
    for (int k = 0; k < 16; ++k) {
        float av = __shfl_xor(a, k, 16);
        o0 += av * wd0[k];
        o1 += av * wd1[k];
    }
    out[(size_t)u * DU_ + l] = o0;
    out[(size_t)u * DU_ + l + 16] = o1;
}

// ---------------------------------------------------------------------------
extern "C" void kernel_launch(void* const* d_in, const int* in_sizes, int n_in,
                              void* d_out, int out_size, void* d_ws, size_t ws_size,
                              hipStream_t stream) {
    const float* q     = (const float*)d_in[0];
    const float* f     = (const float*)d_in[1];
    const int*   docid = (const int*)  d_in[2];
    const float* ct    = (const float*)d_in[3];
    const float* emb   = (const float*)d_in[4];
    const float* Wx    = (const float*)d_in[5];
    const float* Wh    = (const float*)d_in[6];
    const float* brnn  = (const float*)d_in[7];
    const float* Wd    = (const float*)d_in[8];
    const float* bd    = (const float*)d_in[9];
    float* out = (float*)d_out;

    float* pre = (float*)d_ws;                                   // 26.2 MB
    unsigned short* WThi = (unsigned short*)((char*)d_ws + (size_t)U_ * T_ * H_ * 4);
    unsigned short* WTlo = WThi + 16 * KPAD;

    k_wprep<<<(16 * KPAD + 255) / 256, 256, 0, stream>>>(Wx, WThi, WTlo);
    k_pre_f<<<(U_ * T_) / 256, 256, 0, stream>>>(f, WThi, WTlo, pre);
    k_emb<<<(U_ * T_) / 256, 256, 0, stream>>>(q, docid, ct, emb, Wx, brnn, pre);
    k_rnn<<<(U_ * H_) / 64, 64, 0, stream>>>(pre, docid, Wh, Wd, bd, out);
}

// Round 13
// 152.448 us; speedup vs baseline: 1.8591x; 1.1446x over previous
//
#include <hip/hip_runtime.h>

#define U_   2048
#define T_   200
#define H_   16
#define DU_  32
#define KP   288    // 9 K-slabs of 32: f(224, 200 real) | emb(32) | q+ct(11)+pad

typedef __attribute__((ext_vector_type(8))) short bf16x8;
typedef __attribute__((ext_vector_type(4))) float f32x4;

__device__ __forceinline__ unsigned short bf16_rne(float x) {
    unsigned u = __float_as_uint(x);
    return (unsigned short)((u + 0x7FFFu + ((u >> 16) & 1u)) >> 16);
}

// 8 f32 -> hi/lo bf16x8 via residual split (R11-proven manual packing)
__device__ __forceinline__ void cvt8(const float* x, bf16x8& hi, bf16x8& lo) {
    union { bf16x8 v; unsigned u[4]; } H, L;
#pragma unroll
    for (int i = 0; i < 4; ++i) {
        const unsigned short h0 = bf16_rne(x[2 * i]), h1 = bf16_rne(x[2 * i + 1]);
        const float r0 = x[2 * i]     - __uint_as_float((unsigned)h0 << 16);
        const float r1 = x[2 * i + 1] - __uint_as_float((unsigned)h1 << 16);
        H.u[i] = (unsigned)h0 | ((unsigned)h1 << 16);
        L.u[i] = (unsigned)bf16_rne(r0) | ((unsigned)bf16_rne(r1) << 16);
    }
    hi = H.v; lo = L.v;
}

// ---------------------------------------------------------------------------
// Kernel 0: pack ALL of Wx (f rows 43..242 | emb rows 0..31 | q rows 32..41 +
// ct row 263) into B-matrix [n=16][KP=288] bf16 hi/lo, zeros in pad cols.
// ---------------------------------------------------------------------------
__global__ __launch_bounds__(256) void k_wprep(
    const float* __restrict__ Wx,
    unsigned short* __restrict__ WThi, unsigned short* __restrict__ WTlo)
{
    const int idx = blockIdx.x * 256 + threadIdx.x;
    if (idx >= 16 * KP) return;
    const int n = idx / KP, k = idx - n * KP;
    const int s = k >> 5, kk = k & 31;
    float wv = 0.f;
    if (s < 7)       { if (k < 200) wv = Wx[(43 + k) * H_ + n]; }
    else if (s == 7) { wv = Wx[kk * H_ + n]; }
    else             { if (kk < 10) wv = Wx[(32 + kk) * H_ + n];
                       else if (kk == 10) wv = Wx[263 * H_ + n]; }
    const unsigned short h = bf16_rne(wv);
    WThi[idx] = h;
    WTlo[idx] = bf16_rne(wv - __uint_as_float((unsigned)h << 16));
}

// ---------------------------------------------------------------------------
// Kernel 1: pre[pos,h] = brnn[h] + x[pos,:].Wx[:,h]  — fully fused via MFMA.
// Wave = 16 consecutive positions = ONE CONTIGUOUS 12800B f-block = 800
// granules = 13 load rounds/lane (R12 bug: staged only 4 rounds -> rows
// 4..15 garbage; fixed here). Reg->LDS f32 pane (rows padded to 204 floats),
// cvt-to-bf16 at fragment read; 9 K-slabs x 3 MFMA (hi/lo residual).
// 4 independent waves/block, private panes, NO barriers.
// ---------------------------------------------------------------------------
__global__ __launch_bounds__(256, 3) void k_pre(
    const float* __restrict__ qh, const float* __restrict__ f,
    const int* __restrict__ docid, const float* __restrict__ ct,
    const float* __restrict__ emb,
    const unsigned short* __restrict__ WThi,
    const unsigned short* __restrict__ WTlo,
    const float* __restrict__ brnn, float* __restrict__ pre)
{
    __shared__ float pane[4][16 * 204];          // 52224 B -> 3 blocks/CU
    const int t = threadIdx.x, l = t & 63, w = t >> 6;
    const int tile = blockIdx.x * 4 + w;         // 25600 tiles
    const int rbase = tile * 16;
    const int r = l & 15, qd = l >> 4;
    const int pos = rbase + r;

    // ---- 13 contiguous 1KB wave-loads: granules 0..799 of the tile ----
    const char* fsrc = (const char*)f + (size_t)rbase * 800;
    float4 buf[13];
#pragma unroll
    for (int m = 0; m < 13; ++m)
        if (m < 12 || l < 32)                     // round 12: g=768+l < 800
            buf[m] = *(const float4*)(fsrc + (size_t)(m * 64 + l) * 16);

    // ---- direct loads (latency hides under staging/compute) ----
    const int did = docid[pos];
    const float4 e0 = *(const float4*)(emb + (size_t)did * 32 + qd * 8);
    const float4 e1 = *(const float4*)(emb + (size_t)did * 32 + qd * 8 + 4);

    float qx[8];
#pragma unroll
    for (int i = 0; i < 8; ++i) qx[i] = 0.f;
    if (qd == 0) {
#pragma unroll
        for (int j = 0; j < 4; ++j) {
            float2 v = *(const float2*)(qh + (size_t)pos * 10 + 2 * j);
            qx[2 * j] = v.x; qx[2 * j + 1] = v.y;
        }
    } else if (qd == 1) {
        qx[0] = qh[(size_t)pos * 10 + 8];
        qx[1] = qh[(size_t)pos * 10 + 9];
        qx[2] = ct[pos];
    }
    const float bias = brnn[r];

    // ---- stage: granule g -> pane float-offset 4*(g + g/50) = 204*pos+4*col ----
    float* pn = pane[w];
#pragma unroll
    for (int m = 0; m < 13; ++m) {
        const int g = m * 64 + l;
        if (g < 800) *(float4*)(pn + 4 * (g + g / 50)) = buf[m];
    }

    f32x4 acc = {bias, bias, bias, bias};

    // ---- f slabs 0..6 (slab 6: only qd==0 holds real cols 192..199) ----
#pragma unroll
    for (int s = 0; s < 7; ++s) {
        float xr[8];
        if (s < 6 || qd == 0) {
            const float4 a0 = *(const float4*)(pn + r * 204 + s * 32 + qd * 8);
            const float4 a1 = *(const float4*)(pn + r * 204 + s * 32 + qd * 8 + 4);
            xr[0] = a0.x; xr[1] = a0.y; xr[2] = a0.z; xr[3] = a0.w;
            xr[4] = a1.x; xr[5] = a1.y; xr[6] = a1.z; xr[7] = a1.w;
        } else {
#pragma unroll
            for (int i = 0; i < 8; ++i) xr[i] = 0.f;
        }
        bf16x8 ah, al; cvt8(xr, ah, al);
        const bf16x8 bh = *(const bf16x8*)(WThi + r * KP + s * 32 + qd * 8);
        const bf16x8 bl = *(const bf16x8*)(WTlo + r * KP + s * 32 + qd * 8);
        acc = __builtin_amdgcn_mfma_f32_16x16x32_bf16(ah, bh, acc, 0, 0, 0);
        acc = __builtin_amdgcn_mfma_f32_16x16x32_bf16(al, bh, acc, 0, 0, 0);
        acc = __builtin_amdgcn_mfma_f32_16x16x32_bf16(ah, bl, acc, 0, 0, 0);
    }

    // ---- slab 7: emb ----
    {
        float xr[8] = {e0.x, e0.y, e0.z, e0.w, e1.x, e1.y, e1.z, e1.w};
        bf16x8 ah, al; cvt8(xr, ah, al);
        const bf16x8 bh = *(const bf16x8*)(WThi + r * KP + 7 * 32 + qd * 8);
        const bf16x8 bl = *(const bf16x8*)(WTlo + r * KP + 7 * 32 + qd * 8);
        acc = __builtin_amdgcn_mfma_f32_16x16x32_bf16(ah, bh, acc, 0, 0, 0);
        acc = __builtin_amdgcn_mfma_f32_16x16x32_bf16(al, bh, acc, 0, 0, 0);
        acc = __builtin_amdgcn_mfma_f32_16x16x32_bf16(ah, bl, acc, 0, 0, 0);
    }
    // ---- slab 8: q + ct ----
    {
        bf16x8 ah, al; cvt8(qx, ah, al);
        const bf16x8 bh = *(const bf16x8*)(WThi + r * KP + 8 * 32 + qd * 8);
        const bf16x8 bl = *(const bf16x8*)(WTlo + r * KP + 8 * 32 + qd * 8);
        acc = __builtin_amdgcn_mfma_f32_16x16x32_bf16(ah, bh, acc, 0, 0, 0);
        acc = __builtin_amdgcn_mfma_f32_16x16x32_bf16(al, bh, acc, 0, 0, 0);
        acc = __builtin_amdgcn_mfma_f32_16x16x32_bf16(ah, bl, acc, 0, 0, 0);
    }

    // ---- D (m89/R11-verified): col = l&15 = h, row = qd*4 + reg ----
#pragma unroll
    for (int i = 0; i < 4; ++i)
        pre[(size_t)(rbase + qd * 4 + i) * H_ + r] = acc[i];
}

// ---------------------------------------------------------------------------
// Kernel 2: sequential RNN scan + LeakyReLU + Dense.  (unchanged)
// ---------------------------------------------------------------------------
__device__ __forceinline__ float tanh_fast(float x) {
    float e = __expf(2.f * x);
    return 1.f - 2.f / (e + 1.f);
}

__global__ __launch_bounds__(64) void k_rnn(
    const float* __restrict__ pre, const int* __restrict__ docid,
    const float* __restrict__ Wh, const float* __restrict__ Wd,
    const float* __restrict__ bd, float* __restrict__ out)
{
    const int tid = threadIdx.x;
    const int l = tid & 15;
    const int u = (blockIdx.x * 64 + tid) >> 4;

    const float* prow = pre + (size_t)u * T_ * H_;
    const int* drow = docid + (size_t)u * T_;

    float wh[16];
#pragma unroll
    for (int k = 0; k < 16; ++k) wh[k] = Wh[((l ^ k) << 4) | l];

    float h = 0.f;

    float pb0 = prow[0 * H_ + l], pb1 = prow[1 * H_ + l],
          pb2 = prow[2 * H_ + l], pb3 = prow[3 * H_ + l];
    int   m0 = drow[0], m1 = drow[1], m2 = drow[2], m3 = drow[3];

    for (int tb = 0; tb < T_; tb += 4) {
#pragma unroll
        for (int s = 0; s < 4; ++s) {
            float p; int m;
            if      (s == 0) { p = pb0; m = m0; }
            else if (s == 1) { p = pb1; m = m1; }
            else if (s == 2) { p = pb2; m = m2; }
            else             { p = pb3; m = m3; }

            int tn = tb + 4 + s; if (tn > T_ - 1) tn = T_ - 1;
            float pn = prow[tn * H_ + l];
            int   mn = drow[tn];
            if      (s == 0) { pb0 = pn; m0 = mn; }
            else if (s == 1) { pb1 = pn; m1 = mn; }
            else if (s == 2) { pb2 = pn; m2 = mn; }
            else             { pb3 = pn; m3 = mn; }

            float a0 = p, a1 = 0.f, a2 = 0.f, a3 = 0.f;
#pragma unroll
            for (int k = 0; k < 16; k += 4) {
                a0 += __shfl_xor(h, k + 0, 16) * wh[k + 0];
                a1 += __shfl_xor(h, k + 1, 16) * wh[k + 1];
                a2 += __shfl_xor(h, k + 2, 16) * wh[k + 2];
                a3 += __shfl_xor(h, k + 3, 16) * wh[k + 3];
            }
            float accv = (a0 + a1) + (a2 + a3);
            float th = tanh_fast(accv);
            h = (m != 0) ? th : h;
        }
    }

    float a = (h >= 0.f) ? h : 0.3f * h;

    float wd0[16], wd1[16];
#pragma unroll
    for (int k = 0; k < 16; ++k) {
        int j = l ^ k;
        wd0[k] = Wd[j * DU_ + l];
        wd1[k] = Wd[j * DU_ + l + 16];
    }
    float o0 = bd[l], o1 = bd[l + 16];
#pragma unroll
    for (int k = 0; k < 16; ++k) {
        float av = __shfl_xor(a, k, 16);
        o0 += av * wd0[k];
        o1 += av * wd1[k];
    }
    out[(size_t)u * DU_ + l] = o0;
    out[(size_t)u * DU_ + l + 16] = o1;
}

// ---------------------------------------------------------------------------
extern "C" void kernel_launch(void* const* d_in, const int* in_sizes, int n_in,
                              void* d_out, int out_size, void* d_ws, size_t ws_size,
                              hipStream_t stream) {
    const float* qh    = (const float*)d_in[0];
    const float* f     = (const float*)d_in[1];
    const int*   docid = (const int*)  d_in[2];
    const float* ct    = (const float*)d_in[3];
    const float* emb   = (const float*)d_in[4];
    const float* Wx    = (const float*)d_in[5];
    const float* Wh    = (const float*)d_in[6];
    const float* brnn  = (const float*)d_in[7];
    const float* Wd    = (const float*)d_in[8];
    const float* bd    = (const float*)d_in[9];
    float* out = (float*)d_out;

    float* pre = (float*)d_ws;                                   // 26.2 MB
    unsigned short* WThi = (unsigned short*)((char*)d_ws + (size_t)U_ * T_ * H_ * 4);
    unsigned short* WTlo = WThi + 16 * KP;

    k_wprep<<<(16 * KP + 255) / 256, 256, 0, stream>>>(Wx, WThi, WTlo);
    k_pre<<<(U_ * T_) / 64, 256, 0, stream>>>(qh, f, docid, ct, emb, WThi, WTlo, brnn, pre);
    k_rnn<<<(U_ * H_) / 64, 64, 0, stream>>>(pre, docid, Wh, Wd, bd, out);
}